// Round 9
// baseline (24359.966 us; speedup 1.0000x reference)
//
#include <hip/hip_runtime.h>

#define B_ 128
#define T_ 2048
#define H_ 128
#define IN_ 6
#define GRP_ 8            // steps per inner group
#define NGRP_ (T_ / GRP_) // 256
#define CHUNK_ 64         // steps per flag publish
#define FLAG_STRIDE_ 64   // uints between flags (256B)
#define HS_ 144           // LDS row stride in shorts (72 words ≡ 8 mod 32 → 2-way)
#define NBLK_ 268         // 256 + 12: wrap-pairing of the 24 roles onto 12 CUs

typedef _Float16 f16x8 __attribute__((ext_vector_type(8)));
typedef float    f32x4 __attribute__((ext_vector_type(4)));

__device__ __forceinline__ unsigned short f2h_u(float f) {
  union { _Float16 h; unsigned short u; } v; v.h = (_Float16)f; return v.u;
}
__device__ __forceinline__ unsigned int pack2(float a, float b) {
  return (unsigned int)f2h_u(a) | ((unsigned int)f2h_u(b) << 16);
}
__device__ __forceinline__ float sigf_(float x) { return 1.0f / (1.0f + __expf(-x)); }
__device__ __forceinline__ float tanhf_(float x) {
  x = fminf(fmaxf(x, -15.f), 15.f);
  float e = __expf(2.f * x);
  return (e - 1.f) / (e + 1.f);
}
__device__ __forceinline__ f16x8 load_w8(const float* __restrict__ p) {
  f16x8 r;
#pragma unroll
  for (int i = 0; i < 8; ++i) r[i] = (_Float16)p[i];
  return r;
}

__global__ void init_flags(unsigned int* flags) {
  flags[blockIdx.x * 256 + threadIdx.x] = 0u;
}

// ---------------------------------------------------------------------------
// Persistent pipelined 3-layer LSTM; 24 active roles (layer, batch-group).
// Roles at blockIdx 0-11 and 256-267 so round-robin block->CU placement pairs
// two roles per CU (4 waves/SIMD -> latency hiding); other blocks exit.
// Handoff: region f16 [B][T][128] (plain stores; paired L0/L1 share an XCD L2),
// flags per 64-step chunk (agent release / relaxed-poll + acquire).
// ---------------------------------------------------------------------------
__global__ __launch_bounds__(512, 4)
void lstm_pipe(const float* __restrict__ x,
               const float* __restrict__ Wih0, const float* __restrict__ Whh0,
               const float* __restrict__ bih0, const float* __restrict__ bhh0,
               const float* __restrict__ Wih1, const float* __restrict__ Whh1,
               const float* __restrict__ bih1, const float* __restrict__ bhh1,
               const float* __restrict__ Wih2, const float* __restrict__ Whh2,
               const float* __restrict__ bih2, const float* __restrict__ bhh2,
               unsigned short* __restrict__ region,
               unsigned int* __restrict__ state_h,
               unsigned int* __restrict__ flags)
{
  // ---- role remap: pair (L0,bg)+(L1,bg) on CU bg; L2 roles pair with each other
  const int bid = blockIdx.x;
  int role;
  if      (bid < 8)                  role = 0 * 8 + bid;          // L0 bg 0..7
  else if (bid < 12)                 role = 2 * 8 + (bid - 8);    // L2 bg 0..3
  else if (bid >= 256 && bid < 264)  role = 1 * 8 + (bid - 256);  // L1 bg 0..7
  else if (bid >= 264 && bid < 268)  role = 2 * 8 + 4 + (bid - 264); // L2 bg 4..7
  else return;

  const int layer = role >> 3;
  const int bg    = role & 7;
  const int tid   = threadIdx.x;
  const int lane  = tid & 63;
  const int wv    = tid >> 6;       // 0..7: owns units [16wv,16wv+16)
  const int n16   = lane & 15;      // batch within group
  const int quad  = lane >> 4;

  const float* Wih = (layer == 0) ? Wih0 : ((layer == 1) ? Wih1 : Wih2);
  const float* Whh = (layer == 0) ? Whh0 : ((layer == 1) ? Whh1 : Whh2);
  const float* bih = (layer == 0) ? bih0 : ((layer == 1) ? bih1 : bih2);
  const float* bhh = (layer == 0) ? bhh0 : ((layer == 1) ? bhh1 : bhh2);

  __shared__ unsigned short hstate[2][16][HS_];
  __shared__ unsigned short hbufL[GRP_][16][HS_];
  __shared__ unsigned short xbuf[GRP_][16][8];
  __shared__ int s_have;

  // ---- weights -> register A-frags
  f16x8 whh[4][4];
#pragma unroll
  for (int j = 0; j < 4; ++j)
#pragma unroll
    for (int kc = 0; kc < 4; ++kc)
      whh[j][kc] = load_w8(Whh + (size_t)(j * 128 + 16 * wv + n16) * H_ + kc * 32 + quad * 8);

  f16x8 wih[4][4];
  if (layer) {
#pragma unroll
    for (int j = 0; j < 4; ++j)
#pragma unroll
      for (int kc = 0; kc < 4; ++kc)
        wih[j][kc] = load_w8(Wih + (size_t)(j * 128 + 16 * wv + n16) * H_ + kc * 32 + quad * 8);
  }
  f16x8 wx[4];
#pragma unroll
  for (int j = 0; j < 4; ++j)
#pragma unroll
    for (int i = 0; i < 8; ++i) wx[j][i] = (_Float16)0.f;
  if (!layer && quad == 0) {
#pragma unroll
    for (int j = 0; j < 4; ++j) {
      const float* p = Wih + (size_t)(j * 128 + 16 * wv + n16) * IN_;
#pragma unroll
      for (int i = 0; i < IN_; ++i) wx[j][i] = (_Float16)p[i];
    }
  }

  // bias folded into whh-chain C-init
  f32x4 bias4[4];
#pragma unroll
  for (int j = 0; j < 4; ++j)
#pragma unroll
    for (int r = 0; r < 4; ++r) {
      int row = j * 128 + 16 * wv + quad * 4 + r;
      bias4[j][r] = bih[row] + bhh[row];
    }

  f32x4 c4 = {0.f, 0.f, 0.f, 0.f};
  const f32x4 z4 = {0.f, 0.f, 0.f, 0.f};

  for (int i = tid; i < (2 * 16 * HS_) / 2; i += 512) ((unsigned int*)hstate)[i] = 0u;

  unsigned int* flag_in  = (layer > 0) ? &flags[((layer - 1) * 8 + bg) * FLAG_STRIDE_] : nullptr;
  unsigned int* flag_out = (layer < 2) ? &flags[(layer * 8 + bg) * FLAG_STRIDE_] : nullptr;

  uint4 sreg[4];
  uint4 xreg = {0u, 0u, 0u, 0u};
  const int sn_h = tid >> 5, st_h = (tid >> 2) & 7, sq_h = tid & 3;
  const int sn_x = tid >> 3, st_x = tid & 7;

  int have = 0;

  // consumer wait: relaxed poll, acquire finalize (one L2-inv per chunk)
#define WAIT_FOR(need_)                                                          \
  do {                                                                           \
    if (have < (need_)) {                                                        \
      if (tid == 0) {                                                            \
        int v = (int)__hip_atomic_load(flag_in, __ATOMIC_RELAXED,                \
                                       __HIP_MEMORY_SCOPE_AGENT);                \
        while (v < (need_)) {                                                    \
          __builtin_amdgcn_s_sleep(4);                                           \
          v = (int)__hip_atomic_load(flag_in, __ATOMIC_RELAXED,                  \
                                     __HIP_MEMORY_SCOPE_AGENT);                  \
        }                                                                        \
        (void)__hip_atomic_load(flag_in, __ATOMIC_ACQUIRE,                       \
                                __HIP_MEMORY_SCOPE_AGENT);                       \
        s_have = v;                                                              \
      }                                                                          \
      __syncthreads();                                                           \
      have = s_have;                                                             \
    }                                                                            \
  } while (0)

  // ---- pre-stage group 0
  if (layer) WAIT_FOR(1);
  __syncthreads();
  if (layer) {
    const uint4* gp = (const uint4*)(region + ((size_t)(bg * 16 + sn_h) * T_ + st_h) * H_ + sq_h * 32);
#pragma unroll
    for (int i = 0; i < 4; ++i) sreg[i] = gp[i];
    uint4* lp = (uint4*)&hbufL[st_h][sn_h][sq_h * 32];
#pragma unroll
    for (int i = 0; i < 4; ++i) lp[i] = sreg[i];
  } else if (tid < 128) {
    const float* xp = x + ((size_t)(bg * 16 + sn_x) * T_ + st_x) * IN_;
    xreg.x = pack2(xp[0], xp[1]); xreg.y = pack2(xp[2], xp[3]);
    xreg.z = pack2(xp[4], xp[5]); xreg.w = 0u;
    *(uint4*)&xbuf[st_x][sn_x][0] = xreg;
  }
  __syncthreads();

  unsigned int d0[GRP_], d1[GRP_];

  for (int g = 0; g < NGRP_; ++g) {
    int gs = (g + 1 < NGRP_) ? (g + 1) : g;

    if (layer) WAIT_FOR((8 * gs + 7) / CHUNK_ + 1);

    // issue next group's staging loads (consumed at group end)
    if (layer) {
      const uint4* gp = (const uint4*)(region + ((size_t)(bg * 16 + sn_h) * T_ + (8 * gs + st_h)) * H_ + sq_h * 32);
#pragma unroll
      for (int i = 0; i < 4; ++i) sreg[i] = gp[i];
    } else if (tid < 128) {
      const float* xp = x + ((size_t)(bg * 16 + sn_x) * T_ + (8 * gs + st_x)) * IN_;
      xreg.x = pack2(xp[0], xp[1]); xreg.y = pack2(xp[2], xp[3]);
      xreg.z = pack2(xp[4], xp[5]); xreg.w = 0u;
    }

    // ---- 8 recurrence steps
#pragma unroll
    for (int s = 0; s < GRP_; ++s) {
      const int rp = s & 1, wp = rp ^ 1;
      const int ko = quad * 8;

      f16x8 hs[4];
#pragma unroll
      for (int kc = 0; kc < 4; ++kc)
        hs[kc] = *(const f16x8*)&hstate[rp][n16][kc * 32 + ko];

      f32x4 acc[4];
      if (layer) {
        f16x8 hi[4];
#pragma unroll
        for (int kc = 0; kc < 4; ++kc)
          hi[kc] = *(const f16x8*)&hbufL[s][n16][kc * 32 + ko];
#pragma unroll
        for (int j = 0; j < 4; ++j) {
          f32x4 aw = bias4[j];   // whh chain (4 deep)
          f32x4 ai = z4;         // wih chain (4 deep, independent)
#pragma unroll
          for (int kc = 0; kc < 4; ++kc) {
            aw = __builtin_amdgcn_mfma_f32_16x16x32_f16(whh[j][kc], hs[kc], aw, 0, 0, 0);
            ai = __builtin_amdgcn_mfma_f32_16x16x32_f16(wih[j][kc], hi[kc], ai, 0, 0, 0);
          }
#pragma unroll
          for (int r = 0; r < 4; ++r) acc[j][r] = aw[r] + ai[r];
        }
      } else {
        f16x8 xi;
#pragma unroll
        for (int i = 0; i < 8; ++i) xi[i] = (_Float16)0.f;
        if (quad == 0) xi = *(const f16x8*)&xbuf[s][n16][0];
#pragma unroll
        for (int j = 0; j < 4; ++j) {
          f32x4 aw = bias4[j];
#pragma unroll
          for (int kc = 0; kc < 4; ++kc)
            aw = __builtin_amdgcn_mfma_f32_16x16x32_f16(whh[j][kc], hs[kc], aw, 0, 0, 0);
          f32x4 ai = __builtin_amdgcn_mfma_f32_16x16x32_f16(wx[j], xi, z4, 0, 0, 0);
#pragma unroll
          for (int r = 0; r < 4; ++r) acc[j][r] = aw[r] + ai[r];
        }
      }

      float hv4[4];
#pragma unroll
      for (int r = 0; r < 4; ++r) {
        float i_ = sigf_(acc[0][r]);
        float f_ = sigf_(acc[1][r]);
        float g_ = tanhf_(acc[2][r]);
        float o_ = sigf_(acc[3][r]);
        float cc = f_ * c4[r] + i_ * g_;
        c4[r] = cc;
        hv4[r] = o_ * tanhf_(cc);
      }
      unsigned int u0 = pack2(hv4[0], hv4[1]);
      unsigned int u1 = pack2(hv4[2], hv4[3]);
      d0[s] = u0; d1[s] = u1;
      uint2 hw; hw.x = u0; hw.y = u1;
      *(uint2*)&hstate[wp][n16][16 * wv + quad * 4] = hw;
      __syncthreads();
    }

    // deferred h-sequence stores (plain: paired consumer shares this XCD's L2)
    if (layer < 2) {
#pragma unroll
      for (int s = 0; s < GRP_; ++s) {
        size_t off = ((size_t)(bg * 16 + n16) * T_ + (8 * g + s)) * H_ + 16 * wv + quad * 4;
        uint2 hw; hw.x = d0[s]; hw.y = d1[s];
        *(uint2*)(region + off) = hw;
      }
    }
    // staged regs -> LDS for next group
    if (layer) {
      uint4* lp = (uint4*)&hbufL[st_h][sn_h][sq_h * 32];
#pragma unroll
      for (int i = 0; i < 4; ++i) lp[i] = sreg[i];
    } else if (tid < 128) {
      *(uint4*)&xbuf[st_x][sn_x][0] = xreg;
    }
    __syncthreads();  // drains region stores (vmcnt) + publishes LDS

    // producer: publish once per chunk
    if (layer < 2 && ((8 * (g + 1)) % CHUNK_) == 0 && tid == 0) {
      __hip_atomic_store(flag_out, (unsigned int)((8 * (g + 1)) / CHUNK_),
                         __ATOMIC_RELEASE, __HIP_MEMORY_SCOPE_AGENT);
    }
  }
#undef WAIT_FOR

  if (layer == 2) {
    state_h[(bg * 16 + n16) * 64 + 8 * wv + 2 * quad]     = d0[GRP_ - 1];
    state_h[(bg * 16 + n16) * 64 + 8 * wv + 2 * quad + 1] = d1[GRP_ - 1];
  }
}

// ---------------------------------------------------------------------------
__global__ void head_kernel(const unsigned int* __restrict__ state_h,
                            const float* __restrict__ Wout,
                            const float* __restrict__ bout,
                            float* __restrict__ out)
{
  int b = threadIdx.x;  // 128 threads, 1 block
  float s = bout[0];
  for (int j = 0; j < 64; ++j) {
    unsigned int p = state_h[b * 64 + j];
    union { unsigned short u; _Float16 h; } lo, hi;
    lo.u = (unsigned short)(p & 0xffffu);
    hi.u = (unsigned short)(p >> 16);
    s += (float)lo.h * Wout[2 * j] + (float)hi.h * Wout[2 * j + 1];
  }
  out[b] = s;
}

// ---------------------------------------------------------------------------
extern "C" void kernel_launch(void* const* d_in, const int* in_sizes, int n_in,
                              void* d_out, int out_size, void* d_ws, size_t ws_size,
                              hipStream_t stream)
{
  const float* x = (const float*)d_in[0];
  const float* Wih[3] = {(const float*)d_in[1], (const float*)d_in[5], (const float*)d_in[9]};
  const float* Whh[3] = {(const float*)d_in[2], (const float*)d_in[6], (const float*)d_in[10]};
  const float* bih[3] = {(const float*)d_in[3], (const float*)d_in[7], (const float*)d_in[11]};
  const float* bhh[3] = {(const float*)d_in[4], (const float*)d_in[8], (const float*)d_in[12]};
  const float* Wout = (const float*)d_in[13];
  const float* bout = (const float*)d_in[14];
  float* out = (float*)d_out;

  char* ws = (char*)d_ws;
  size_t off = 0;
  unsigned short* region = (unsigned short*)(ws + off); off += (size_t)B_ * T_ * H_ * 2;  // 64 MiB
  unsigned int* state_h  = (unsigned int*)(ws + off);   off += (size_t)B_ * 64 * 4;
  off = (off + 255) & ~(size_t)255;
  unsigned int* flags    = (unsigned int*)(ws + off);   off += 16 * FLAG_STRIDE_ * 4;

  init_flags<<<4, 256, 0, stream>>>(flags);
  lstm_pipe<<<NBLK_, 512, 0, stream>>>(x,
      Wih[0], Whh[0], bih[0], bhh[0],
      Wih[1], Whh[1], bih[1], bhh[1],
      Wih[2], Whh[2], bih[2], bhh[2],
      region, state_h, flags);
  head_kernel<<<1, 128, 0, stream>>>(state_h, Wout, bout, out);
}

// Round 10
// 3361.713 us; speedup vs baseline: 7.2463x; 7.2463x over previous
//
#include <hip/hip_runtime.h>

#define B_ 128
#define T_ 2048
#define H_ 128
#define IN_ 6
#define GRP_ 8            // steps per inner group
#define NGRP_ (T_ / GRP_) // 256
#define CHUNK_ 32         // steps per flag publish
#define FLAG_STRIDE_ 64   // uints between flags (256B)
#define HS_ 144           // LDS row stride in shorts (72 words ≡ 8 mod 32 → 2-way)

typedef _Float16 f16x8 __attribute__((ext_vector_type(8)));
typedef float    f32x4 __attribute__((ext_vector_type(4)));

__device__ __forceinline__ unsigned short f2h_u(float f) {
  union { _Float16 h; unsigned short u; } v; v.h = (_Float16)f; return v.u;
}
__device__ __forceinline__ unsigned int pack2(float a, float b) {
  return (unsigned int)f2h_u(a) | ((unsigned int)f2h_u(b) << 16);
}
// fast sigmoid/tanh: v_exp + v_rcp (no IEEE divide sequence).
// Overflow-safe: exp->inf => rcp->0 => correct saturation.
__device__ __forceinline__ float sigf_(float x) {
  return __builtin_amdgcn_rcpf(1.0f + __expf(-x));
}
__device__ __forceinline__ float tanhf_(float x) {
  return 2.0f * __builtin_amdgcn_rcpf(1.0f + __expf(-2.0f * x)) - 1.0f;
}
__device__ __forceinline__ f16x8 load_w8(const float* __restrict__ p) {
  f16x8 r;
#pragma unroll
  for (int i = 0; i < 8; ++i) r[i] = (_Float16)p[i];
  return r;
}

__global__ void init_flags(unsigned int* flags) {
  flags[blockIdx.x * 256 + threadIdx.x] = 0u;
}

// ---------------------------------------------------------------------------
// Persistent pipelined 3-layer LSTM. 24 WGs: layer = bid>>3, batch-group = bid&7.
// Handoff: region f16 [B][T][128], flags per 32-step chunk (agent release /
// relaxed-poll + acquire). Activations via v_exp+v_rcp only.
// ---------------------------------------------------------------------------
__global__ __launch_bounds__(512, 2)
void lstm_pipe(const float* __restrict__ x,
               const float* __restrict__ Wih0, const float* __restrict__ Whh0,
               const float* __restrict__ bih0, const float* __restrict__ bhh0,
               const float* __restrict__ Wih1, const float* __restrict__ Whh1,
               const float* __restrict__ bih1, const float* __restrict__ bhh1,
               const float* __restrict__ Wih2, const float* __restrict__ Whh2,
               const float* __restrict__ bih2, const float* __restrict__ bhh2,
               unsigned short* __restrict__ region,
               unsigned int* __restrict__ state_h,
               unsigned int* __restrict__ flags)
{
  const int layer = blockIdx.x >> 3;
  const int bg    = blockIdx.x & 7;
  const int tid   = threadIdx.x;
  const int lane  = tid & 63;
  const int wv    = tid >> 6;       // 0..7: owns units [16wv,16wv+16)
  const int n16   = lane & 15;      // batch within group
  const int quad  = lane >> 4;

  const float* Wih = (layer == 0) ? Wih0 : ((layer == 1) ? Wih1 : Wih2);
  const float* Whh = (layer == 0) ? Whh0 : ((layer == 1) ? Whh1 : Whh2);
  const float* bih = (layer == 0) ? bih0 : ((layer == 1) ? bih1 : bih2);
  const float* bhh = (layer == 0) ? bhh0 : ((layer == 1) ? bhh1 : bhh2);

  __shared__ unsigned short hstate[2][16][HS_];
  __shared__ unsigned short hbufL[GRP_][16][HS_];
  __shared__ unsigned short xbuf[GRP_][16][8];
  __shared__ int s_have;

  // ---- weights -> register A-frags
  f16x8 whh[4][4];
#pragma unroll
  for (int j = 0; j < 4; ++j)
#pragma unroll
    for (int kc = 0; kc < 4; ++kc)
      whh[j][kc] = load_w8(Whh + (size_t)(j * 128 + 16 * wv + n16) * H_ + kc * 32 + quad * 8);

  f16x8 wih[4][4];
  if (layer) {
#pragma unroll
    for (int j = 0; j < 4; ++j)
#pragma unroll
      for (int kc = 0; kc < 4; ++kc)
        wih[j][kc] = load_w8(Wih + (size_t)(j * 128 + 16 * wv + n16) * H_ + kc * 32 + quad * 8);
  }
  f16x8 wx[4];
#pragma unroll
  for (int j = 0; j < 4; ++j)
#pragma unroll
    for (int i = 0; i < 8; ++i) wx[j][i] = (_Float16)0.f;
  if (!layer && quad == 0) {
#pragma unroll
    for (int j = 0; j < 4; ++j) {
      const float* p = Wih + (size_t)(j * 128 + 16 * wv + n16) * IN_;
#pragma unroll
      for (int i = 0; i < IN_; ++i) wx[j][i] = (_Float16)p[i];
    }
  }

  // bias folded into whh-chain C-init
  f32x4 bias4[4];
#pragma unroll
  for (int j = 0; j < 4; ++j)
#pragma unroll
    for (int r = 0; r < 4; ++r) {
      int row = j * 128 + 16 * wv + quad * 4 + r;
      bias4[j][r] = bih[row] + bhh[row];
    }

  f32x4 c4 = {0.f, 0.f, 0.f, 0.f};
  const f32x4 z4 = {0.f, 0.f, 0.f, 0.f};

  for (int i = tid; i < (2 * 16 * HS_) / 2; i += 512) ((unsigned int*)hstate)[i] = 0u;

  unsigned int* flag_in  = (layer > 0) ? &flags[((layer - 1) * 8 + bg) * FLAG_STRIDE_] : nullptr;
  unsigned int* flag_out = (layer < 2) ? &flags[(layer * 8 + bg) * FLAG_STRIDE_] : nullptr;

  uint4 sreg[4];
  uint4 xreg = {0u, 0u, 0u, 0u};
  const int sn_h = tid >> 5, st_h = (tid >> 2) & 7, sq_h = tid & 3;
  const int sn_x = tid >> 3, st_x = tid & 7;

  int have = 0;

  // consumer wait: relaxed poll, acquire finalize (one L2-inv per chunk)
#define WAIT_FOR(need_)                                                          \
  do {                                                                           \
    if (have < (need_)) {                                                        \
      if (tid == 0) {                                                            \
        int v = (int)__hip_atomic_load(flag_in, __ATOMIC_RELAXED,                \
                                       __HIP_MEMORY_SCOPE_AGENT);                \
        while (v < (need_)) {                                                    \
          __builtin_amdgcn_s_sleep(4);                                           \
          v = (int)__hip_atomic_load(flag_in, __ATOMIC_RELAXED,                  \
                                     __HIP_MEMORY_SCOPE_AGENT);                  \
        }                                                                        \
        (void)__hip_atomic_load(flag_in, __ATOMIC_ACQUIRE,                       \
                                __HIP_MEMORY_SCOPE_AGENT);                       \
        s_have = v;                                                              \
      }                                                                          \
      __syncthreads();                                                           \
      have = s_have;                                                             \
    }                                                                            \
  } while (0)

  // ---- pre-stage group 0
  if (layer) WAIT_FOR(1);
  __syncthreads();
  if (layer) {
    const uint4* gp = (const uint4*)(region + ((size_t)(bg * 16 + sn_h) * T_ + st_h) * H_ + sq_h * 32);
#pragma unroll
    for (int i = 0; i < 4; ++i) sreg[i] = gp[i];
    uint4* lp = (uint4*)&hbufL[st_h][sn_h][sq_h * 32];
#pragma unroll
    for (int i = 0; i < 4; ++i) lp[i] = sreg[i];
  } else if (tid < 128) {
    const float* xp = x + ((size_t)(bg * 16 + sn_x) * T_ + st_x) * IN_;
    xreg.x = pack2(xp[0], xp[1]); xreg.y = pack2(xp[2], xp[3]);
    xreg.z = pack2(xp[4], xp[5]); xreg.w = 0u;
    *(uint4*)&xbuf[st_x][sn_x][0] = xreg;
  }
  __syncthreads();

  unsigned int d0[GRP_], d1[GRP_];

  for (int g = 0; g < NGRP_; ++g) {
    int gs = (g + 1 < NGRP_) ? (g + 1) : g;

    if (layer) WAIT_FOR((8 * gs + 7) / CHUNK_ + 1);

    // issue next group's staging loads (consumed at group end)
    if (layer) {
      const uint4* gp = (const uint4*)(region + ((size_t)(bg * 16 + sn_h) * T_ + (8 * gs + st_h)) * H_ + sq_h * 32);
#pragma unroll
      for (int i = 0; i < 4; ++i) sreg[i] = gp[i];
    } else if (tid < 128) {
      const float* xp = x + ((size_t)(bg * 16 + sn_x) * T_ + (8 * gs + st_x)) * IN_;
      xreg.x = pack2(xp[0], xp[1]); xreg.y = pack2(xp[2], xp[3]);
      xreg.z = pack2(xp[4], xp[5]); xreg.w = 0u;
    }

    // ---- 8 recurrence steps
#pragma unroll
    for (int s = 0; s < GRP_; ++s) {
      const int rp = s & 1, wp = rp ^ 1;
      const int ko = quad * 8;

      f16x8 hs[4];
#pragma unroll
      for (int kc = 0; kc < 4; ++kc)
        hs[kc] = *(const f16x8*)&hstate[rp][n16][kc * 32 + ko];

      f32x4 acc[4];
      if (layer) {
        f16x8 hi[4];
#pragma unroll
        for (int kc = 0; kc < 4; ++kc)
          hi[kc] = *(const f16x8*)&hbufL[s][n16][kc * 32 + ko];
#pragma unroll
        for (int j = 0; j < 4; ++j) {
          f32x4 aw = bias4[j];   // whh chain
          f32x4 ai = z4;         // wih chain (independent)
#pragma unroll
          for (int kc = 0; kc < 4; ++kc) {
            aw = __builtin_amdgcn_mfma_f32_16x16x32_f16(whh[j][kc], hs[kc], aw, 0, 0, 0);
            ai = __builtin_amdgcn_mfma_f32_16x16x32_f16(wih[j][kc], hi[kc], ai, 0, 0, 0);
          }
#pragma unroll
          for (int r = 0; r < 4; ++r) acc[j][r] = aw[r] + ai[r];
        }
      } else {
        f16x8 xi;
#pragma unroll
        for (int i = 0; i < 8; ++i) xi[i] = (_Float16)0.f;
        if (quad == 0) xi = *(const f16x8*)&xbuf[s][n16][0];
#pragma unroll
        for (int j = 0; j < 4; ++j) {
          f32x4 aw = bias4[j];
#pragma unroll
          for (int kc = 0; kc < 4; ++kc)
            aw = __builtin_amdgcn_mfma_f32_16x16x32_f16(whh[j][kc], hs[kc], aw, 0, 0, 0);
          f32x4 ai = __builtin_amdgcn_mfma_f32_16x16x32_f16(wx[j], xi, z4, 0, 0, 0);
#pragma unroll
          for (int r = 0; r < 4; ++r) acc[j][r] = aw[r] + ai[r];
        }
      }

      float hv4[4];
#pragma unroll
      for (int r = 0; r < 4; ++r) {
        float i_ = sigf_(acc[0][r]);
        float f_ = sigf_(acc[1][r]);
        float g_ = tanhf_(acc[2][r]);
        float o_ = sigf_(acc[3][r]);
        float cc = f_ * c4[r] + i_ * g_;
        c4[r] = cc;
        hv4[r] = o_ * tanhf_(cc);
      }
      unsigned int u0 = pack2(hv4[0], hv4[1]);
      unsigned int u1 = pack2(hv4[2], hv4[3]);
      d0[s] = u0; d1[s] = u1;
      uint2 hw; hw.x = u0; hw.y = u1;
      *(uint2*)&hstate[wp][n16][16 * wv + quad * 4] = hw;
      __syncthreads();
    }

    // deferred h-sequence stores
    if (layer < 2) {
#pragma unroll
      for (int s = 0; s < GRP_; ++s) {
        size_t off = ((size_t)(bg * 16 + n16) * T_ + (8 * g + s)) * H_ + 16 * wv + quad * 4;
        uint2 hw; hw.x = d0[s]; hw.y = d1[s];
        *(uint2*)(region + off) = hw;
      }
    }
    // staged regs -> LDS for next group
    if (layer) {
      uint4* lp = (uint4*)&hbufL[st_h][sn_h][sq_h * 32];
#pragma unroll
      for (int i = 0; i < 4; ++i) lp[i] = sreg[i];
    } else if (tid < 128) {
      *(uint4*)&xbuf[st_x][sn_x][0] = xreg;
    }
    __syncthreads();  // drains region stores (vmcnt) + publishes LDS

    // producer: publish once per chunk
    if (layer < 2 && ((8 * (g + 1)) % CHUNK_) == 0 && tid == 0) {
      __hip_atomic_store(flag_out, (unsigned int)((8 * (g + 1)) / CHUNK_),
                         __ATOMIC_RELEASE, __HIP_MEMORY_SCOPE_AGENT);
    }
  }
#undef WAIT_FOR

  if (layer == 2) {
    state_h[(bg * 16 + n16) * 64 + 8 * wv + 2 * quad]     = d0[GRP_ - 1];
    state_h[(bg * 16 + n16) * 64 + 8 * wv + 2 * quad + 1] = d1[GRP_ - 1];
  }
}

// ---------------------------------------------------------------------------
__global__ void head_kernel(const unsigned int* __restrict__ state_h,
                            const float* __restrict__ Wout,
                            const float* __restrict__ bout,
                            float* __restrict__ out)
{
  int b = threadIdx.x;  // 128 threads, 1 block
  float s = bout[0];
  for (int j = 0; j < 64; ++j) {
    unsigned int p = state_h[b * 64 + j];
    union { unsigned short u; _Float16 h; } lo, hi;
    lo.u = (unsigned short)(p & 0xffffu);
    hi.u = (unsigned short)(p >> 16);
    s += (float)lo.h * Wout[2 * j] + (float)hi.h * Wout[2 * j + 1];
  }
  out[b] = s;
}

// ---------------------------------------------------------------------------
extern "C" void kernel_launch(void* const* d_in, const int* in_sizes, int n_in,
                              void* d_out, int out_size, void* d_ws, size_t ws_size,
                              hipStream_t stream)
{
  const float* x = (const float*)d_in[0];
  const float* Wih[3] = {(const float*)d_in[1], (const float*)d_in[5], (const float*)d_in[9]};
  const float* Whh[3] = {(const float*)d_in[2], (const float*)d_in[6], (const float*)d_in[10]};
  const float* bih[3] = {(const float*)d_in[3], (const float*)d_in[7], (const float*)d_in[11]};
  const float* bhh[3] = {(const float*)d_in[4], (const float*)d_in[8], (const float*)d_in[12]};
  const float* Wout = (const float*)d_in[13];
  const float* bout = (const float*)d_in[14];
  float* out = (float*)d_out;

  char* ws = (char*)d_ws;
  size_t off = 0;
  unsigned short* region = (unsigned short*)(ws + off); off += (size_t)B_ * T_ * H_ * 2;  // 64 MiB
  unsigned int* state_h  = (unsigned int*)(ws + off);   off += (size_t)B_ * 64 * 4;
  off = (off + 255) & ~(size_t)255;
  unsigned int* flags    = (unsigned int*)(ws + off);   off += 16 * FLAG_STRIDE_ * 4;

  init_flags<<<4, 256, 0, stream>>>(flags);
  lstm_pipe<<<24, 512, 0, stream>>>(x,
      Wih[0], Whh[0], bih[0], bhh[0],
      Wih[1], Whh[1], bih[1], bhh[1],
      Wih[2], Whh[2], bih[2], bhh[2],
      region, state_h, flags);
  head_kernel<<<1, 128, 0, stream>>>(state_h, Wout, bout, out);
}